// Round 5
// baseline (414.345 us; speedup 1.0000x reference)
//
#include <hip/hip_runtime.h>
#include <stdint.h>

#define B_ 2
#define S_ 2048
#define DIM_ 2048
#define H_ 16
#define KVH_ 4
#define HD_ 128

typedef short short8 __attribute__((ext_vector_type(8)));
typedef float f4 __attribute__((ext_vector_type(4)));
typedef unsigned short u16;

// softmax scale folded into Q: 1/sqrt(128) * log2(e)
#define KSCALE (0.08838834764831845f * 1.4426950408889634f)

__device__ __forceinline__ float bf2f(u16 u) {
    union { unsigned int i; float f; } c; c.i = ((unsigned int)u) << 16; return c.f;
}
__device__ __forceinline__ u16 f2bf(float f) {
    union { float f; unsigned int i; } c; c.f = f;
    return (u16)((c.i + 0x7fffu + ((c.i >> 16) & 1u)) >> 16);
}

// async global->LDS, 16B per lane; LDS dest is wave-uniform base + lane*16
#define GLDS16(gp, lp) \
    __builtin_amdgcn_global_load_lds((const __attribute__((address_space(1))) unsigned int*)(gp), \
                                     (__attribute__((address_space(3))) unsigned int*)(lp), 16, 0, 0)

// ---------------- fp32 -> bf16 cast ----------------
__global__ void cast4_kernel(const float* __restrict__ in, u16* __restrict__ out, int n4) {
    int i = blockIdx.x * blockDim.x + threadIdx.x;
    if (i < n4) {
        float4 v = ((const float4*)in)[i];
        ushort4 o;
        o.x = f2bf(v.x); o.y = f2bf(v.y); o.z = f2bf(v.z); o.w = f2bf(v.w);
        ((ushort4*)out)[i] = o;
    }
}

// ---------------- GEMM: C[M,N] = A[M,K] @ W[N,K]^T, m97 structure ----------------
template<bool OUT_BF16>
__global__ __launch_bounds__(256) void gemm_bt(const u16* __restrict__ A,
                                               const u16* __restrict__ W,
                                               void* __restrict__ Cout,
                                               int M, int N, int K) {
    __shared__ u16 As[128 * 32];
    __shared__ u16 Bs[128 * 32];
    int t = threadIdx.x, lane = t & 63, w = t >> 6;
    int quad = lane >> 4, l16 = lane & 15;
    int wm = w & 1, wn = w >> 1;
    size_t m0 = (size_t)blockIdx.y * 128, n0 = (size_t)blockIdx.x * 128;

    int c0 = w * 2;
    int ar = c0 * 16 + (lane >> 2);
    int ac = (lane & 3) * 8;
    const u16* Abase = A + (m0 + ar) * (size_t)K + ac;
    const u16* Bbase = W + (n0 + ar) * (size_t)K + ac;
    u16* Adst = As + c0 * 512;
    u16* Bdst = Bs + c0 * 512;

    f4 acc[4][4];
    #pragma unroll
    for (int i = 0; i < 4; i++)
        #pragma unroll
        for (int j = 0; j < 4; j++) acc[i][j] = (f4){0.f, 0.f, 0.f, 0.f};

    int nk = K >> 5;
    for (int kt = 0; kt < nk; kt++) {
        const u16* ga = Abase + kt * 32;
        const u16* gb = Bbase + kt * 32;
        GLDS16(ga, Adst);
        GLDS16(ga + 16 * (size_t)K, Adst + 512);
        GLDS16(gb, Bdst);
        GLDS16(gb + 16 * (size_t)K, Bdst + 512);
        __syncthreads();
        short8 a[4], b[4];
        #pragma unroll
        for (int i = 0; i < 4; i++) a[i] = *(const short8*)&As[(wm * 64 + i * 16 + l16) * 32 + quad * 8];
        #pragma unroll
        for (int j = 0; j < 4; j++) b[j] = *(const short8*)&Bs[(wn * 64 + j * 16 + l16) * 32 + quad * 8];
        #pragma unroll
        for (int i = 0; i < 4; i++)
            #pragma unroll
            for (int j = 0; j < 4; j++)
                acc[i][j] = __builtin_amdgcn_mfma_f32_16x16x32_bf16(a[i], b[j], acc[i][j], 0, 0, 0);
        __syncthreads();
    }
    #pragma unroll
    for (int i = 0; i < 4; i++) {
        size_t row = m0 + wm * 64 + i * 16 + quad * 4;
        #pragma unroll
        for (int j = 0; j < 4; j++) {
            size_t col = n0 + wn * 64 + j * 16 + l16;
            #pragma unroll
            for (int r = 0; r < 4; r++) {
                if (OUT_BF16) ((u16*)Cout)[(row + r) * N + col] = f2bf(acc[i][j][r]);
                else          ((float*)Cout)[(row + r) * N + col] = acc[i][j][r];
            }
        }
    }
}

// ---------------- RoPE + softmax-prescale, in-place on Q cols [0,2048) of QKV ----------------
__global__ void rope_q(u16* __restrict__ QKV, const float* __restrict__ freqs) {
    int pc = blockIdx.x * 256 + threadIdx.x;   // pair index 0..1023
    int row = blockIdx.y;
    int s = row & (S_ - 1);
    int hd2 = pc & 63;
    float2 cs = ((const float2*)freqs)[s * 64 + hd2];
    ushort2* pp = (ushort2*)(QKV + (size_t)row * 3072);
    ushort2 v = pp[pc];
    float x0 = bf2f(v.x), x1 = bf2f(v.y);
    ushort2 ov;
    ov.x = f2bf((x0 * cs.x - x1 * cs.y) * KSCALE);
    ov.y = f2bf((x0 * cs.y + x1 * cs.x) * KSCALE);
    pp[pc] = ov;
}

// ---------------- pack K (with fused RoPE) into MFMA B-fragment order ----------------
// Kp[bk][kt][fid=n*4+c][lane][8] = rope(K)[b, s=kt*64+n*16+l16, kvh, hd=c*32+quad*8+j]
__global__ __launch_bounds__(256) void pack_k(const u16* __restrict__ QKV,
                                              const float* __restrict__ freqs,
                                              u16* __restrict__ Kp) {
    int gid = blockIdx.x * 256 + threadIdx.x;   // 262144
    int lane = gid & 63;
    int fid = (gid >> 6) & 15;
    int kt = (gid >> 10) & 31;
    int bk = gid >> 15;
    int b = bk >> 2, kvh = bk & 3;
    int n = fid >> 2, c = fid & 3;
    int l16 = lane & 15, quad = lane >> 4;
    int s = kt * 64 + n * 16 + l16;
    const u16* src = QKV + (size_t)(b * 2048 + s) * 3072 + 2048 + kvh * 128 + c * 32 + quad * 8;
    short8 v = *(const short8*)src;
    short8 o;
    #pragma unroll
    for (int jp = 0; jp < 4; jp++) {
        int hd2 = c * 16 + quad * 4 + jp;
        float2 cw = ((const float2*)freqs)[s * 64 + hd2];
        float x0 = bf2f((u16)v[2 * jp]), x1 = bf2f((u16)v[2 * jp + 1]);
        o[2 * jp]     = (short)f2bf(x0 * cw.x - x1 * cw.y);
        o[2 * jp + 1] = (short)f2bf(x0 * cw.y + x1 * cw.x);
    }
    *(short8*)&Kp[(size_t)gid * 8] = o;
}

// ---------------- pack V into MFMA B-fragment order (LDS-tile transpose) ----------------
// Vp[bk][kt][fid=nt*2+kc][lane][8] = V[b, s=kt*64+kc*32+quad*8+j, kvh, hd=nt*16+l16]
__global__ __launch_bounds__(256) void pack_v(const u16* __restrict__ QKV, u16* __restrict__ Vp) {
    __shared__ u16 L[64 * 136];
    int bid = blockIdx.x;          // 256 blocks
    int bk = bid & 7, kt = bid >> 3;
    int b = bk >> 2, kvh = bk & 3;
    int t = threadIdx.x;
    const u16* src = QKV + (size_t)(b * 2048 + kt * 64) * 3072 + 2560 + kvh * 128;
    #pragma unroll
    for (int it = 0; it < 4; it++) {
        int idx = t + it * 256;
        int r = idx >> 4, c = idx & 15;
        *(short8*)&L[r * 136 + c * 8] = *(const short8*)(src + (size_t)r * 3072 + c * 8);
    }
    __syncthreads();
    u16* dst = Vp + ((size_t)bk * 32 + kt) * 8192;
    #pragma unroll
    for (int it = 0; it < 4; it++) {
        int idx = t + it * 256;
        int fid = idx >> 6, lane = idx & 63;
        int nt = fid >> 1, kc = fid & 1;
        int l16 = lane & 15, quad = lane >> 4;
        int hd = nt * 16 + l16;
        int s0 = kc * 32 + quad * 8;
        short8 v;
        #pragma unroll
        for (int j = 0; j < 8; j++) v[j] = (short)L[(s0 + j) * 136 + hd];
        *(short8*)&dst[(size_t)idx * 8] = v;
    }
}

// ---------------- Flash attention ----------------
// block = (bk, pr): 4 waves = 4 GQA heads; each wave handles q-tiles qtS=pr, qtL=127-pr
// sharing one staged K/V tile (paired load balance: every block ~33 work units).
// bk = bid&7 -> fixed XCD per kv-head (2MB K/V resident in its L2).
__global__ __launch_bounds__(256, 3) void attn_kernel(const u16* __restrict__ QKV,
                                                      const u16* __restrict__ Kp,
                                                      const u16* __restrict__ Vp,
                                                      u16* __restrict__ Ob) {
    __shared__ u16 Ks[16 * 512];   // 16KB packed K tile
    __shared__ u16 Vs[16 * 512];   // 16KB packed V tile
    __shared__ u16 Ps[8192];       // 16KB: per-wave PL/PS, XOR-swizzled
    int bid = blockIdx.x;
    int bk = bid & 7, pr = bid >> 3;
    int b = bk >> 2, kvh = bk & 3;
    int qtS = pr, qtL = 127 - pr;
    int nktS = (qtS >> 2) + 1, nktL = (qtL >> 2) + 1;
    int t = threadIdx.x, lane = t & 63, w = t >> 6, quad = lane >> 4, l16 = lane & 15;
    int l7 = l16 & 7, hi = l16 >> 3;
    int h = kvh * 4 + w;

    // Q fragments (A-layout, pre-scaled by KSCALE in rope_q)
    short8 qfL[4], qfS[4];
    {
        const u16* qpL = QKV + ((size_t)(b * S_ + qtL * 16 + l16)) * 3072 + h * HD_ + quad * 8;
        const u16* qpS = QKV + ((size_t)(b * S_ + qtS * 16 + l16)) * 3072 + h * HD_ + quad * 8;
        #pragma unroll
        for (int c = 0; c < 4; c++) { qfL[c] = *(const short8*)(qpL + c * 32); qfS[c] = *(const short8*)(qpS + c * 32); }
    }
    short8 ones;
    #pragma unroll
    for (int j = 0; j < 8; j++) ones[j] = (short)0x3F80;

    float mL = -3e38f, mS = -3e38f;
    f4 lsL = (f4){0.f,0.f,0.f,0.f}, lsS = (f4){0.f,0.f,0.f,0.f};
    f4 oL[8], oS[8];
    #pragma unroll
    for (int n = 0; n < 8; n++) { oL[n] = (f4){0.f,0.f,0.f,0.f}; oS[n] = (f4){0.f,0.f,0.f,0.f}; }

    const u16* Kpb = Kp + (size_t)bk * 32 * 8192;
    const u16* Vpb = Vp + (size_t)bk * 32 * 8192;
    u16* PL = Ps + w * 1024;
    u16* PS = Ps + 4096 + w * 1024;

    for (int kt = 0; kt < nktL; kt++) {
        // stage packed K,V tiles: wave w stages fragments w*4..w*4+3 of each
        {
            const u16* ks = Kpb + (size_t)kt * 8192 + (w * 4) * 512 + lane * 8;
            const u16* vs = Vpb + (size_t)kt * 8192 + (w * 4) * 512 + lane * 8;
            #pragma unroll
            for (int i = 0; i < 4; i++) {
                GLDS16(ks + i * 512, &Ks[(w * 4 + i) * 512]);
                GLDS16(vs + i * 512, &Vs[(w * 4 + i) * 512]);
            }
        }
        __syncthreads();
        bool doS = (kt < nktS);

        // QK^T for both q-tiles off one K-fragment read
        f4 scL[4], scS[4];
        #pragma unroll
        for (int n = 0; n < 4; n++) { scL[n] = (f4){0.f,0.f,0.f,0.f}; scS[n] = (f4){0.f,0.f,0.f,0.f}; }
        #pragma unroll
        for (int n = 0; n < 4; n++) {
            #pragma unroll
            for (int c = 0; c < 4; c++) {
                short8 kf = *(const short8*)&Ks[(n * 4 + c) * 512 + lane * 8];
                scL[n] = __builtin_amdgcn_mfma_f32_16x16x32_bf16(qfL[c], kf, scL[n], 0, 0, 0);
                if (doS) scS[n] = __builtin_amdgcn_mfma_f32_16x16x32_bf16(qfS[c], kf, scS[n], 0, 0, 0);
            }
        }

        // ---- L tile: mask (diag only), wave-group max, exp2, pack ----
        {
            if (kt == nktL - 1) {
                int qrow0 = qtL * 16 + quad * 4;
                #pragma unroll
                for (int n = 0; n < 4; n++) {
                    int colg = kt * 64 + n * 16 + l16;
                    #pragma unroll
                    for (int r = 0; r < 4; r++)
                        scL[n][r] = (colg <= qrow0 + r) ? scL[n][r] : -3e38f;
                }
            }
            float gm = fmaxf(fmaxf(scL[0][0], scL[0][1]), fmaxf(scL[0][2], scL[0][3]));
            #pragma unroll
            for (int n = 1; n < 4; n++)
                gm = fmaxf(gm, fmaxf(fmaxf(scL[n][0], scL[n][1]), fmaxf(scL[n][2], scL[n][3])));
            #pragma unroll
            for (int off = 1; off < 64; off <<= 1) gm = fmaxf(gm, __shfl_xor(gm, off, 64));
            float mnew = fmaxf(mL, gm);
            if (mnew > mL) {          // wave-uniform branch
                float al = exp2f(mL - mnew);
                mL = mnew;
                #pragma unroll
                for (int r = 0; r < 4; r++) lsL[r] *= al;
                #pragma unroll
                for (int nt = 0; nt < 8; nt++)
                    #pragma unroll
                    for (int r = 0; r < 4; r++) oL[nt][r] *= al;
            }
            #pragma unroll
            for (int n = 0; n < 4; n++) {
                #pragma unroll
                for (int r = 0; r < 4; r++) {
                    float p = exp2f(scL[n][r] - mL);
                    union { float f; unsigned int u; } cv; cv.f = p;
                    int row = quad * 4 + r;
                    int sw = (n * 2 + hi) ^ (row & 7);
                    PL[row * 64 + sw * 8 + l7] = (u16)(cv.u >> 16);
                }
            }
        }
        // ---- S tile ----
        if (doS) {
            if (kt == nktS - 1) {
                int qrow0 = qtS * 16 + quad * 4;
                #pragma unroll
                for (int n = 0; n < 4; n++) {
                    int colg = kt * 64 + n * 16 + l16;
                    #pragma unroll
                    for (int r = 0; r < 4; r++)
                        scS[n][r] = (colg <= qrow0 + r) ? scS[n][r] : -3e38f;
                }
            }
            float gm = fmaxf(fmaxf(scS[0][0], scS[0][1]), fmaxf(scS[0][2], scS[0][3]));
            #pragma unroll
            for (int n = 1; n < 4; n++)
                gm = fmaxf(gm, fmaxf(fmaxf(scS[n][0], scS[n][1]), fmaxf(scS[n][2], scS[n][3])));
            #pragma unroll
            for (int off = 1; off < 64; off <<= 1) gm = fmaxf(gm, __shfl_xor(gm, off, 64));
            float mnew = fmaxf(mS, gm);
            if (mnew > mS) {
                float al = exp2f(mS - mnew);
                mS = mnew;
                #pragma unroll
                for (int r = 0; r < 4; r++) lsS[r] *= al;
                #pragma unroll
                for (int nt = 0; nt < 8; nt++)
                    #pragma unroll
                    for (int r = 0; r < 4; r++) oS[nt][r] *= al;
            }
            #pragma unroll
            for (int n = 0; n < 4; n++) {
                #pragma unroll
                for (int r = 0; r < 4; r++) {
                    float p = exp2f(scS[n][r] - mS);
                    union { float f; unsigned int u; } cv; cv.f = p;
                    int row = quad * 4 + r;
                    int sw = (n * 2 + hi) ^ (row & 7);
                    PS[row * 64 + sw * 8 + l7] = (u16)(cv.u >> 16);
                }
            }
        }
        __asm__ volatile("s_waitcnt lgkmcnt(0)" ::: "memory");

        // ---- PV: O += P @ V ; l += P @ ones (one V-fragment read serves both tiles) ----
        #pragma unroll
        for (int kc = 0; kc < 2; kc++) {
            short8 aL = *(const short8*)&PL[l16 * 64 + (((kc * 4 + quad) ^ l7) << 3)];
            lsL = __builtin_amdgcn_mfma_f32_16x16x32_bf16(aL, ones, lsL, 0, 0, 0);
            short8 aS;
            if (doS) {
                aS = *(const short8*)&PS[l16 * 64 + (((kc * 4 + quad) ^ l7) << 3)];
                lsS = __builtin_amdgcn_mfma_f32_16x16x32_bf16(aS, ones, lsS, 0, 0, 0);
            }
            #pragma unroll
            for (int nt = 0; nt < 8; nt++) {
                short8 vf = *(const short8*)&Vs[(nt * 2 + kc) * 512 + lane * 8];
                oL[nt] = __builtin_amdgcn_mfma_f32_16x16x32_bf16(aL, vf, oL[nt], 0, 0, 0);
                if (doS) oS[nt] = __builtin_amdgcn_mfma_f32_16x16x32_bf16(aS, vf, oS[nt], 0, 0, 0);
            }
        }
        __syncthreads();
    }
    // epilogue
    float rlL[4], rlS[4];
    #pragma unroll
    for (int r = 0; r < 4; r++) { rlL[r] = 1.0f / lsL[r]; rlS[r] = 1.0f / lsS[r]; }
    #pragma unroll
    for (int nt = 0; nt < 8; nt++)
        #pragma unroll
        for (int r = 0; r < 4; r++) {
            size_t rowL = (size_t)b * S_ + qtL * 16 + quad * 4 + r;
            size_t rowS = (size_t)b * S_ + qtS * 16 + quad * 4 + r;
            Ob[rowL * 2048 + h * HD_ + nt * 16 + l16] = f2bf(oL[nt][r] * rlL[r]);
            Ob[rowS * 2048 + h * HD_ + nt * 16 + l16] = f2bf(oS[nt][r] * rlS[r]);
        }
}

extern "C" void kernel_launch(void* const* d_in, const int* in_sizes, int n_in,
                              void* d_out, int out_size, void* d_ws, size_t ws_size,
                              hipStream_t stream) {
    const float* x     = (const float*)d_in[0];
    const float* freqs = (const float*)d_in[1];
    const float* wq    = (const float*)d_in[2];
    const float* wk    = (const float*)d_in[3];
    const float* wv    = (const float*)d_in[4];
    const float* wo    = (const float*)d_in[5];
    float* out = (float*)d_out;

    char* p = (char*)d_ws;
    u16* xb    = (u16*)p; p += (size_t)4096 * 2048 * 2;   // 16MB
    u16* wqkvb = (u16*)p; p += (size_t)3072 * 2048 * 2;   // 12MB
    u16* wob   = (u16*)p; p += (size_t)2048 * 2048 * 2;   // 8MB
    u16* QKVb  = (u16*)p; p += (size_t)4096 * 3072 * 2;   // 24MB
    u16* Kpb   = (u16*)p; p += (size_t)8 * 32 * 8192 * 2; // 4MB
    u16* Vpb   = (u16*)p; p += (size_t)8 * 32 * 8192 * 2; // 4MB
    u16* attnb = xb;  // reuse

    cast4_kernel<<<8192, 256, 0, stream>>>(x, xb, 2097152);
    cast4_kernel<<<4096, 256, 0, stream>>>(wq, wqkvb, 1048576);
    cast4_kernel<<<1024, 256, 0, stream>>>(wk, wqkvb + (size_t)2048 * 2048, 262144);
    cast4_kernel<<<1024, 256, 0, stream>>>(wv, wqkvb + (size_t)2560 * 2048, 262144);
    cast4_kernel<<<4096, 256, 0, stream>>>(wo, wob, 1048576);

    gemm_bt<true><<<dim3(24, 32), 256, 0, stream>>>(xb, wqkvb, QKVb, 4096, 3072, 2048);

    rope_q<<<dim3(4, 4096), 256, 0, stream>>>(QKVb, freqs);

    pack_k<<<1024, 256, 0, stream>>>(QKVb, freqs, Kpb);
    pack_v<<<256, 256, 0, stream>>>(QKVb, Vpb);

    attn_kernel<<<512, 256, 0, stream>>>(QKVb, Kpb, Vpb, attnb);

    gemm_bt<false><<<dim3(16, 32), 256, 0, stream>>>(attnb, wob, out, 4096, 2048, 2048);
}

// Round 6
// 345.612 us; speedup vs baseline: 1.1989x; 1.1989x over previous
//
#include <hip/hip_runtime.h>
#include <stdint.h>

#define B_ 2
#define S_ 2048
#define DIM_ 2048
#define H_ 16
#define KVH_ 4
#define HD_ 128

typedef short short8 __attribute__((ext_vector_type(8)));
typedef float f4 __attribute__((ext_vector_type(4)));
typedef unsigned short u16;

// softmax scale folded into Q: 1/sqrt(128) * log2(e)
#define KSCALE (0.08838834764831845f * 1.4426950408889634f)

__device__ __forceinline__ float bf2f(u16 u) {
    union { unsigned int i; float f; } c; c.i = ((unsigned int)u) << 16; return c.f;
}
__device__ __forceinline__ u16 f2bf(float f) {
    union { float f; unsigned int i; } c; c.f = f;
    return (u16)((c.i + 0x7fffu + ((c.i >> 16) & 1u)) >> 16);
}

// async global->LDS, 16B per lane; LDS dest is wave-uniform base + lane*16
#define GLDS16(gp, lp) \
    __builtin_amdgcn_global_load_lds((const __attribute__((address_space(1))) unsigned int*)(gp), \
                                     (__attribute__((address_space(3))) unsigned int*)(lp), 16, 0, 0)

// ---------------- fp32 -> bf16 cast ----------------
__global__ void cast4_kernel(const float* __restrict__ in, u16* __restrict__ out, int n4) {
    int i = blockIdx.x * blockDim.x + threadIdx.x;
    if (i < n4) {
        float4 v = ((const float4*)in)[i];
        ushort4 o;
        o.x = f2bf(v.x); o.y = f2bf(v.y); o.z = f2bf(v.z); o.w = f2bf(v.w);
        ((ushort4*)out)[i] = o;
    }
}

// ---------------- GEMM: C[M,N] = A[M,K] @ W[N,K]^T, m97 structure ----------------
template<bool OUT_BF16>
__global__ __launch_bounds__(256) void gemm_bt(const u16* __restrict__ A,
                                               const u16* __restrict__ W,
                                               void* __restrict__ Cout,
                                               int M, int N, int K) {
    __shared__ u16 As[128 * 32];
    __shared__ u16 Bs[128 * 32];
    int t = threadIdx.x, lane = t & 63, w = t >> 6;
    int quad = lane >> 4, l16 = lane & 15;
    int wm = w & 1, wn = w >> 1;
    size_t m0 = (size_t)blockIdx.y * 128, n0 = (size_t)blockIdx.x * 128;

    int c0 = w * 2;
    int ar = c0 * 16 + (lane >> 2);
    int ac = (lane & 3) * 8;
    const u16* Abase = A + (m0 + ar) * (size_t)K + ac;
    const u16* Bbase = W + (n0 + ar) * (size_t)K + ac;
    u16* Adst = As + c0 * 512;
    u16* Bdst = Bs + c0 * 512;

    f4 acc[4][4];
    #pragma unroll
    for (int i = 0; i < 4; i++)
        #pragma unroll
        for (int j = 0; j < 4; j++) acc[i][j] = (f4){0.f, 0.f, 0.f, 0.f};

    int nk = K >> 5;
    for (int kt = 0; kt < nk; kt++) {
        const u16* ga = Abase + kt * 32;
        const u16* gb = Bbase + kt * 32;
        GLDS16(ga, Adst);
        GLDS16(ga + 16 * (size_t)K, Adst + 512);
        GLDS16(gb, Bdst);
        GLDS16(gb + 16 * (size_t)K, Bdst + 512);
        __syncthreads();
        short8 a[4], b[4];
        #pragma unroll
        for (int i = 0; i < 4; i++) a[i] = *(const short8*)&As[(wm * 64 + i * 16 + l16) * 32 + quad * 8];
        #pragma unroll
        for (int j = 0; j < 4; j++) b[j] = *(const short8*)&Bs[(wn * 64 + j * 16 + l16) * 32 + quad * 8];
        #pragma unroll
        for (int i = 0; i < 4; i++)
            #pragma unroll
            for (int j = 0; j < 4; j++)
                acc[i][j] = __builtin_amdgcn_mfma_f32_16x16x32_bf16(a[i], b[j], acc[i][j], 0, 0, 0);
        __syncthreads();
    }
    #pragma unroll
    for (int i = 0; i < 4; i++) {
        size_t row = m0 + wm * 64 + i * 16 + quad * 4;
        #pragma unroll
        for (int j = 0; j < 4; j++) {
            size_t col = n0 + wn * 64 + j * 16 + l16;
            #pragma unroll
            for (int r = 0; r < 4; r++) {
                if (OUT_BF16) ((u16*)Cout)[(row + r) * N + col] = f2bf(acc[i][j][r]);
                else          ((float*)Cout)[(row + r) * N + col] = acc[i][j][r];
            }
        }
    }
}

// ---------------- RoPE + softmax-prescale, in-place on Q cols [0,2048) of QKV ----------------
__global__ void rope_q(u16* __restrict__ QKV, const float* __restrict__ freqs) {
    int pc = blockIdx.x * 256 + threadIdx.x;   // pair index 0..1023
    int row = blockIdx.y;
    int s = row & (S_ - 1);
    int hd2 = pc & 63;
    float2 cs = ((const float2*)freqs)[s * 64 + hd2];
    ushort2* pp = (ushort2*)(QKV + (size_t)row * 3072);
    ushort2 v = pp[pc];
    float x0 = bf2f(v.x), x1 = bf2f(v.y);
    ushort2 ov;
    ov.x = f2bf((x0 * cs.x - x1 * cs.y) * KSCALE);
    ov.y = f2bf((x0 * cs.y + x1 * cs.x) * KSCALE);
    pp[pc] = ov;
}

// ---------------- pack K (with fused RoPE) into MFMA B-fragment order ----------------
// Kp[bk][kt][fid=n*4+c][lane][8] = rope(K)[b, s=kt*64+n*16+l16, kvh, hd=c*32+quad*8+j]
__global__ __launch_bounds__(256) void pack_k(const u16* __restrict__ QKV,
                                              const float* __restrict__ freqs,
                                              u16* __restrict__ Kp) {
    int gid = blockIdx.x * 256 + threadIdx.x;   // 262144
    int lane = gid & 63;
    int fid = (gid >> 6) & 15;
    int kt = (gid >> 10) & 31;
    int bk = gid >> 15;
    int b = bk >> 2, kvh = bk & 3;
    int n = fid >> 2, c = fid & 3;
    int l16 = lane & 15, quad = lane >> 4;
    int s = kt * 64 + n * 16 + l16;
    const u16* src = QKV + (size_t)(b * 2048 + s) * 3072 + 2048 + kvh * 128 + c * 32 + quad * 8;
    short8 v = *(const short8*)src;
    short8 o;
    #pragma unroll
    for (int jp = 0; jp < 4; jp++) {
        int hd2 = c * 16 + quad * 4 + jp;
        float2 cw = ((const float2*)freqs)[s * 64 + hd2];
        float x0 = bf2f((u16)v[2 * jp]), x1 = bf2f((u16)v[2 * jp + 1]);
        o[2 * jp]     = (short)f2bf(x0 * cw.x - x1 * cw.y);
        o[2 * jp + 1] = (short)f2bf(x0 * cw.y + x1 * cw.x);
    }
    *(short8*)&Kp[(size_t)gid * 8] = o;
}

// ---------------- pack V into MFMA B-fragment order (LDS-tile transpose) ----------------
// Vp[bk][kt][fid=nt*2+kc][lane][8] = V[b, s=kt*64+kc*32+quad*8+j, kvh, hd=nt*16+l16]
__global__ __launch_bounds__(256) void pack_v(const u16* __restrict__ QKV, u16* __restrict__ Vp) {
    __shared__ u16 L[64 * 136];
    int bid = blockIdx.x;          // 256 blocks
    int bk = bid & 7, kt = bid >> 3;
    int b = bk >> 2, kvh = bk & 3;
    int t = threadIdx.x;
    const u16* src = QKV + (size_t)(b * 2048 + kt * 64) * 3072 + 2560 + kvh * 128;
    #pragma unroll
    for (int it = 0; it < 4; it++) {
        int idx = t + it * 256;
        int r = idx >> 4, c = idx & 15;
        *(short8*)&L[r * 136 + c * 8] = *(const short8*)(src + (size_t)r * 3072 + c * 8);
    }
    __syncthreads();
    u16* dst = Vp + ((size_t)bk * 32 + kt) * 8192;
    #pragma unroll
    for (int it = 0; it < 4; it++) {
        int idx = t + it * 256;
        int fid = idx >> 6, lane = idx & 63;
        int nt = fid >> 1, kc = fid & 1;
        int l16 = lane & 15, quad = lane >> 4;
        int hd = nt * 16 + l16;
        int s0 = kc * 32 + quad * 8;
        short8 v;
        #pragma unroll
        for (int j = 0; j < 8; j++) v[j] = (short)L[(s0 + j) * 136 + hd];
        *(short8*)&dst[(size_t)idx * 8] = v;
    }
}

// ---------------- Flash attention ----------------
// block = (bk, qt): 4 waves = 4 GQA heads of one kv-head, one 16-row q-tile each.
// LDS = 16+16+8 = 40KB -> 4 blocks/CU (16 waves/CU). Grid qt-descending.
// VGPR budget: o(32)+sc(16)+qf(16)+ls(4)+misc ~ 90 <= 128 cap of (256,4) -> no spill.
__global__ __launch_bounds__(256, 4) void attn_kernel(const u16* __restrict__ QKV,
                                                      const u16* __restrict__ Kp,
                                                      const u16* __restrict__ Vp,
                                                      u16* __restrict__ Ob) {
    __shared__ u16 Ks[16 * 512];   // 16KB packed K tile
    __shared__ u16 Vs[16 * 512];   // 16KB packed V tile
    __shared__ u16 Ps[4 * 1024];   // 8KB: per-wave P (16x64), XOR-swizzled
    int bid = blockIdx.x;
    int bk = bid & 7;
    int qt = 127 - (bid >> 3);
    int b = bk >> 2, kvh = bk & 3;
    int t = threadIdx.x, lane = t & 63, w = t >> 6, quad = lane >> 4, l16 = lane & 15;
    int l7 = l16 & 7, hi = l16 >> 3;
    int h = kvh * 4 + w;

    // Q fragments (A-layout, pre-scaled by KSCALE in rope_q)
    short8 qf[4];
    {
        const u16* qp = QKV + ((size_t)(b * S_ + qt * 16 + l16)) * 3072 + h * HD_ + quad * 8;
        #pragma unroll
        for (int c = 0; c < 4; c++) qf[c] = *(const short8*)(qp + c * 32);
    }
    short8 ones;
    #pragma unroll
    for (int j = 0; j < 8; j++) ones[j] = (short)0x3F80;

    float m_i = -3e38f;
    f4 ls = (f4){0.f, 0.f, 0.f, 0.f};
    f4 o[8];
    #pragma unroll
    for (int n = 0; n < 8; n++) o[n] = (f4){0.f, 0.f, 0.f, 0.f};

    const u16* Kpb = Kp + (size_t)bk * 32 * 8192;
    const u16* Vpb = Vp + (size_t)bk * 32 * 8192;
    u16* P = Ps + w * 1024;
    int nkt = (qt >> 2) + 1;

    for (int kt = 0; kt < nkt; kt++) {
        // stage packed K,V tiles: wave w stages fragments w*4..w*4+3 of each
        {
            const u16* ks = Kpb + (size_t)kt * 8192 + (w * 4) * 512 + lane * 8;
            const u16* vs = Vpb + (size_t)kt * 8192 + (w * 4) * 512 + lane * 8;
            #pragma unroll
            for (int i = 0; i < 4; i++) {
                GLDS16(ks + i * 512, &Ks[(w * 4 + i) * 512]);
                GLDS16(vs + i * 512, &Vs[(w * 4 + i) * 512]);
            }
        }
        __syncthreads();

        // QK^T (Q pre-scaled -> scores already in log2 domain)
        f4 sc[4];
        #pragma unroll
        for (int n = 0; n < 4; n++) sc[n] = (f4){0.f, 0.f, 0.f, 0.f};
        #pragma unroll
        for (int n = 0; n < 4; n++) {
            #pragma unroll
            for (int c = 0; c < 4; c++) {
                short8 kf = *(const short8*)&Ks[(n * 4 + c) * 512 + lane * 8];
                sc[n] = __builtin_amdgcn_mfma_f32_16x16x32_bf16(qf[c], kf, sc[n], 0, 0, 0);
            }
        }
        // causal mask only on the diagonal k-tile
        if (kt == nkt - 1) {
            int qrow0 = qt * 16 + quad * 4;
            #pragma unroll
            for (int n = 0; n < 4; n++) {
                int colg = kt * 64 + n * 16 + l16;
                #pragma unroll
                for (int r = 0; r < 4; r++)
                    sc[n][r] = (colg <= qrow0 + r) ? sc[n][r] : -3e38f;
            }
        }
        // wave-group max: one scalar m per wave (exact: any per-row constant works)
        float gm = fmaxf(fmaxf(sc[0][0], sc[0][1]), fmaxf(sc[0][2], sc[0][3]));
        #pragma unroll
        for (int n = 1; n < 4; n++)
            gm = fmaxf(gm, fmaxf(fmaxf(sc[n][0], sc[n][1]), fmaxf(sc[n][2], sc[n][3])));
        #pragma unroll
        for (int off = 1; off < 64; off <<= 1) gm = fmaxf(gm, __shfl_xor(gm, off, 64));
        float mnew = fmaxf(m_i, gm);
        if (mnew > m_i) {              // wave-uniform branch
            float al = exp2f(m_i - mnew);
            m_i = mnew;
            #pragma unroll
            for (int r = 0; r < 4; r++) ls[r] *= al;
            #pragma unroll
            for (int nt = 0; nt < 8; nt++)
                #pragma unroll
                for (int r = 0; r < 4; r++) o[nt][r] *= al;
        }
        // P = exp2(s - m), truncate-pack to bf16, swizzled LDS write
        #pragma unroll
        for (int n = 0; n < 4; n++) {
            #pragma unroll
            for (int r = 0; r < 4; r++) {
                float p = exp2f(sc[n][r] - m_i);
                union { float f; unsigned int u; } cv; cv.f = p;
                int row = quad * 4 + r;
                int sw = (n * 2 + hi) ^ (row & 7);
                P[row * 64 + sw * 8 + l7] = (u16)(cv.u >> 16);
            }
        }
        __asm__ volatile("s_waitcnt lgkmcnt(0)" ::: "memory");

        // PV: O += P @ V ; l += P @ ones (MFMA row-sum)
        #pragma unroll
        for (int kc = 0; kc < 2; kc++) {
            short8 af = *(const short8*)&P[l16 * 64 + (((kc * 4 + quad) ^ l7) << 3)];
            ls = __builtin_amdgcn_mfma_f32_16x16x32_bf16(af, ones, ls, 0, 0, 0);
            #pragma unroll
            for (int nt = 0; nt < 8; nt++) {
                short8 vf = *(const short8*)&Vs[(nt * 2 + kc) * 512 + lane * 8];
                o[nt] = __builtin_amdgcn_mfma_f32_16x16x32_bf16(af, vf, o[nt], 0, 0, 0);
            }
        }
        __syncthreads();
    }
    // epilogue
    float rl[4];
    #pragma unroll
    for (int r = 0; r < 4; r++) rl[r] = 1.0f / ls[r];
    #pragma unroll
    for (int nt = 0; nt < 8; nt++)
        #pragma unroll
        for (int r = 0; r < 4; r++) {
            size_t row = (size_t)b * S_ + qt * 16 + quad * 4 + r;
            Ob[row * 2048 + h * HD_ + nt * 16 + l16] = f2bf(o[nt][r] * rl[r]);
        }
}

extern "C" void kernel_launch(void* const* d_in, const int* in_sizes, int n_in,
                              void* d_out, int out_size, void* d_ws, size_t ws_size,
                              hipStream_t stream) {
    const float* x     = (const float*)d_in[0];
    const float* freqs = (const float*)d_in[1];
    const float* wq    = (const float*)d_in[2];
    const float* wk    = (const float*)d_in[3];
    const float* wv    = (const float*)d_in[4];
    const float* wo    = (const float*)d_in[5];
    float* out = (float*)d_out;

    char* p = (char*)d_ws;
    u16* xb    = (u16*)p; p += (size_t)4096 * 2048 * 2;   // 16MB
    u16* wqkvb = (u16*)p; p += (size_t)3072 * 2048 * 2;   // 12MB
    u16* wob   = (u16*)p; p += (size_t)2048 * 2048 * 2;   // 8MB
    u16* QKVb  = (u16*)p; p += (size_t)4096 * 3072 * 2;   // 24MB
    u16* Kpb   = (u16*)p; p += (size_t)8 * 32 * 8192 * 2; // 4MB
    u16* Vpb   = (u16*)p; p += (size_t)8 * 32 * 8192 * 2; // 4MB
    u16* attnb = xb;  // reuse

    cast4_kernel<<<8192, 256, 0, stream>>>(x, xb, 2097152);
    cast4_kernel<<<4096, 256, 0, stream>>>(wq, wqkvb, 1048576);
    cast4_kernel<<<1024, 256, 0, stream>>>(wk, wqkvb + (size_t)2048 * 2048, 262144);
    cast4_kernel<<<1024, 256, 0, stream>>>(wv, wqkvb + (size_t)2560 * 2048, 262144);
    cast4_kernel<<<4096, 256, 0, stream>>>(wo, wob, 1048576);

    gemm_bt<true><<<dim3(24, 32), 256, 0, stream>>>(xb, wqkvb, QKVb, 4096, 3072, 2048);

    rope_q<<<dim3(4, 4096), 256, 0, stream>>>(QKVb, freqs);

    pack_k<<<1024, 256, 0, stream>>>(QKVb, freqs, Kpb);
    pack_v<<<256, 256, 0, stream>>>(QKVb, Vpb);

    attn_kernel<<<1024, 256, 0, stream>>>(QKVb, Kpb, Vpb, attnb);

    gemm_bt<false><<<dim3(16, 32), 256, 0, stream>>>(attnb, wob, out, 4096, 2048, 2048);
}

// Round 7
// 324.023 us; speedup vs baseline: 1.2788x; 1.0666x over previous
//
#include <hip/hip_runtime.h>
#include <stdint.h>

#define B_ 2
#define S_ 2048
#define DIM_ 2048
#define H_ 16
#define KVH_ 4
#define HD_ 128

typedef short short8 __attribute__((ext_vector_type(8)));
typedef float f4 __attribute__((ext_vector_type(4)));
typedef unsigned short u16;

// softmax scale folded into Q: 1/sqrt(128) * log2(e)
#define KSCALE (0.08838834764831845f * 1.4426950408889634f)

__device__ __forceinline__ float bf2f(u16 u) {
    union { unsigned int i; float f; } c; c.i = ((unsigned int)u) << 16; return c.f;
}
__device__ __forceinline__ u16 f2bf(float f) {
    union { float f; unsigned int i; } c; c.f = f;
    return (u16)((c.i + 0x7fffu + ((c.i >> 16) & 1u)) >> 16);
}

// async global->LDS, 16B per lane; LDS dest is wave-uniform base + lane*16
#define GLDS16(gp, lp) \
    __builtin_amdgcn_global_load_lds((const __attribute__((address_space(1))) unsigned int*)(gp), \
                                     (__attribute__((address_space(3))) unsigned int*)(lp), 16, 0, 0)

// ---------------- fused fp32 -> bf16 cast of all 5 tensors ----------------
__global__ void cast_all(const float* __restrict__ x,  const float* __restrict__ wq,
                         const float* __restrict__ wk, const float* __restrict__ wv,
                         const float* __restrict__ wo,
                         u16* __restrict__ xb, u16* __restrict__ wqkvb, u16* __restrict__ wob) {
    int i = blockIdx.x * 256 + threadIdx.x;   // float4 index, total 4718592
    const float4* src; ushort4* dst; int j;
    if (i < 2097152)      { src = (const float4*)x;  dst = (ushort4*)xb;                 j = i; }
    else if (i < 3145728) { src = (const float4*)wq; dst = (ushort4*)wqkvb;              j = i - 2097152; }
    else if (i < 3407872) { src = (const float4*)wk; dst = (ushort4*)wqkvb + 1048576;    j = i - 3145728; }
    else if (i < 3670016) { src = (const float4*)wv; dst = (ushort4*)wqkvb + 1310720;    j = i - 3407872; }
    else                  { src = (const float4*)wo; dst = (ushort4*)wob;                j = i - 3670016; }
    float4 v = src[j];
    ushort4 o;
    o.x = f2bf(v.x); o.y = f2bf(v.y); o.z = f2bf(v.z); o.w = f2bf(v.w);
    dst[j] = o;
}

// ---------------- GEMM: C[M,N] = A[M,K] @ W[N,K]^T, m97 structure ----------------
template<bool OUT_BF16>
__global__ __launch_bounds__(256) void gemm_bt(const u16* __restrict__ A,
                                               const u16* __restrict__ W,
                                               void* __restrict__ Cout,
                                               int M, int N, int K) {
    __shared__ u16 As[128 * 32];
    __shared__ u16 Bs[128 * 32];
    int t = threadIdx.x, lane = t & 63, w = t >> 6;
    int quad = lane >> 4, l16 = lane & 15;
    int wm = w & 1, wn = w >> 1;
    size_t m0 = (size_t)blockIdx.y * 128, n0 = (size_t)blockIdx.x * 128;

    int c0 = w * 2;
    int ar = c0 * 16 + (lane >> 2);
    int ac = (lane & 3) * 8;
    const u16* Abase = A + (m0 + ar) * (size_t)K + ac;
    const u16* Bbase = W + (n0 + ar) * (size_t)K + ac;
    u16* Adst = As + c0 * 512;
    u16* Bdst = Bs + c0 * 512;

    f4 acc[4][4];
    #pragma unroll
    for (int i = 0; i < 4; i++)
        #pragma unroll
        for (int j = 0; j < 4; j++) acc[i][j] = (f4){0.f, 0.f, 0.f, 0.f};

    int nk = K >> 5;
    for (int kt = 0; kt < nk; kt++) {
        const u16* ga = Abase + kt * 32;
        const u16* gb = Bbase + kt * 32;
        GLDS16(ga, Adst);
        GLDS16(ga + 16 * (size_t)K, Adst + 512);
        GLDS16(gb, Bdst);
        GLDS16(gb + 16 * (size_t)K, Bdst + 512);
        __syncthreads();
        short8 a[4], b[4];
        #pragma unroll
        for (int i = 0; i < 4; i++) a[i] = *(const short8*)&As[(wm * 64 + i * 16 + l16) * 32 + quad * 8];
        #pragma unroll
        for (int j = 0; j < 4; j++) b[j] = *(const short8*)&Bs[(wn * 64 + j * 16 + l16) * 32 + quad * 8];
        #pragma unroll
        for (int i = 0; i < 4; i++)
            #pragma unroll
            for (int j = 0; j < 4; j++)
                acc[i][j] = __builtin_amdgcn_mfma_f32_16x16x32_bf16(a[i], b[j], acc[i][j], 0, 0, 0);
        __syncthreads();
    }
    #pragma unroll
    for (int i = 0; i < 4; i++) {
        size_t row = m0 + wm * 64 + i * 16 + quad * 4;
        #pragma unroll
        for (int j = 0; j < 4; j++) {
            size_t col = n0 + wn * 64 + j * 16 + l16;
            #pragma unroll
            for (int r = 0; r < 4; r++) {
                if (OUT_BF16) ((u16*)Cout)[(row + r) * N + col] = f2bf(acc[i][j][r]);
                else          ((float*)Cout)[(row + r) * N + col] = acc[i][j][r];
            }
        }
    }
}

// ---------------- RoPE + softmax-prescale, in-place on Q cols [0,2048) of QKV ----------------
__global__ void rope_q(u16* __restrict__ QKV, const float* __restrict__ freqs) {
    int pc = blockIdx.x * 256 + threadIdx.x;   // pair index 0..1023
    int row = blockIdx.y;
    int s = row & (S_ - 1);
    int hd2 = pc & 63;
    float2 cs = ((const float2*)freqs)[s * 64 + hd2];
    ushort2* pp = (ushort2*)(QKV + (size_t)row * 3072);
    ushort2 v = pp[pc];
    float x0 = bf2f(v.x), x1 = bf2f(v.y);
    ushort2 ov;
    ov.x = f2bf((x0 * cs.x - x1 * cs.y) * KSCALE);
    ov.y = f2bf((x0 * cs.y + x1 * cs.x) * KSCALE);
    pp[pc] = ov;
}

// ---------------- pack K (with fused RoPE) into MFMA B-fragment order ----------------
// Kp[bk][kt][fid=n*4+c][lane][8] = rope(K)[b, s=kt*64+n*16+l16, kvh, hd=c*32+quad*8+j]
__global__ __launch_bounds__(256) void pack_k(const u16* __restrict__ QKV,
                                              const float* __restrict__ freqs,
                                              u16* __restrict__ Kp) {
    int gid = blockIdx.x * 256 + threadIdx.x;   // 262144
    int lane = gid & 63;
    int fid = (gid >> 6) & 15;
    int kt = (gid >> 10) & 31;
    int bk = gid >> 15;
    int b = bk >> 2, kvh = bk & 3;
    int n = fid >> 2, c = fid & 3;
    int l16 = lane & 15, quad = lane >> 4;
    int s = kt * 64 + n * 16 + l16;
    const u16* src = QKV + (size_t)(b * 2048 + s) * 3072 + 2048 + kvh * 128 + c * 32 + quad * 8;
    short8 v = *(const short8*)src;
    short8 o;
    #pragma unroll
    for (int jp = 0; jp < 4; jp++) {
        int hd2 = c * 16 + quad * 4 + jp;
        float2 cw = ((const float2*)freqs)[s * 64 + hd2];
        float x0 = bf2f((u16)v[2 * jp]), x1 = bf2f((u16)v[2 * jp + 1]);
        o[2 * jp]     = (short)f2bf(x0 * cw.x - x1 * cw.y);
        o[2 * jp + 1] = (short)f2bf(x0 * cw.y + x1 * cw.x);
    }
    *(short8*)&Kp[(size_t)gid * 8] = o;
}

// ---------------- pack V into MFMA B-fragment order (LDS-tile transpose) ----------------
// Vp[bk][kt][fid=nt*2+kc][lane][8] = V[b, s=kt*64+kc*32+quad*8+j, kvh, hd=nt*16+l16]
__global__ __launch_bounds__(256) void pack_v(const u16* __restrict__ QKV, u16* __restrict__ Vp) {
    __shared__ u16 L[64 * 136];
    int bid = blockIdx.x;          // 256 blocks
    int bk = bid & 7, kt = bid >> 3;
    int b = bk >> 2, kvh = bk & 3;
    int t = threadIdx.x;
    const u16* src = QKV + (size_t)(b * 2048 + kt * 64) * 3072 + 2560 + kvh * 128;
    #pragma unroll
    for (int it = 0; it < 4; it++) {
        int idx = t + it * 256;
        int r = idx >> 4, c = idx & 15;
        *(short8*)&L[r * 136 + c * 8] = *(const short8*)(src + (size_t)r * 3072 + c * 8);
    }
    __syncthreads();
    u16* dst = Vp + ((size_t)bk * 32 + kt) * 8192;
    #pragma unroll
    for (int it = 0; it < 4; it++) {
        int idx = t + it * 256;
        int fid = idx >> 6, lane = idx & 63;
        int nt = fid >> 1, kc = fid & 1;
        int l16 = lane & 15, quad = lane >> 4;
        int hd = nt * 16 + l16;
        int s0 = kc * 32 + quad * 8;
        short8 v;
        #pragma unroll
        for (int j = 0; j < 8; j++) v[j] = (short)L[(s0 + j) * 136 + hd];
        *(short8*)&dst[(size_t)idx * 8] = v;
    }
}

// ---------------- Flash attention ----------------
// block = (bk, pr): 4 waves = 4 GQA heads; each wave processes q-tile 127-pr then pr
// SEQUENTIALLY (one softmax state live at a time -> no register doubling).
// Every block does exactly 33-34 k-tile iterations -> uniform work, no tail.
// Grid 512 = 2 blocks/CU everywhere. LDS 40KB. waves_per_eu(2,2) pins VGPR cap at 256
// (prevents the R6 shrink-to-64 + scratch-spill pathology).
__global__ __launch_bounds__(256) __attribute__((amdgpu_waves_per_eu(2, 2)))
void attn_kernel(const u16* __restrict__ QKV,
                 const u16* __restrict__ Kp,
                 const u16* __restrict__ Vp,
                 u16* __restrict__ Ob) {
    __shared__ u16 Ks[16 * 512];   // 16KB packed K tile
    __shared__ u16 Vs[16 * 512];   // 16KB packed V tile
    __shared__ u16 Ps[4 * 1024];   // 8KB: per-wave P (16x64), XOR-swizzled
    int bid = blockIdx.x;          // 512 blocks
    int bk = bid & 7, pr = bid >> 3;   // pr in [0,64)
    int b = bk >> 2, kvh = bk & 3;
    int t = threadIdx.x, lane = t & 63, w = t >> 6, quad = lane >> 4, l16 = lane & 15;
    int l7 = l16 & 7, hi = l16 >> 3;
    int h = kvh * 4 + w;

    short8 ones;
    #pragma unroll
    for (int j = 0; j < 8; j++) ones[j] = (short)0x3F80;

    const u16* Kpb = Kp + (size_t)bk * 32 * 8192;
    const u16* Vpb = Vp + (size_t)bk * 32 * 8192;
    u16* P = Ps + w * 1024;

    for (int ph = 0; ph < 2; ph++) {
        int qt = ph ? pr : 127 - pr;
        int nkt = (qt >> 2) + 1;

        // Q fragments (A-layout, pre-scaled by KSCALE in rope_q)
        short8 qf[4];
        {
            const u16* qp = QKV + ((size_t)(b * S_ + qt * 16 + l16)) * 3072 + h * HD_ + quad * 8;
            #pragma unroll
            for (int c = 0; c < 4; c++) qf[c] = *(const short8*)(qp + c * 32);
        }
        float m_i = -3e38f;
        f4 ls = (f4){0.f, 0.f, 0.f, 0.f};
        f4 o[8];
        #pragma unroll
        for (int n = 0; n < 8; n++) o[n] = (f4){0.f, 0.f, 0.f, 0.f};

        for (int kt = 0; kt < nkt; kt++) {
            // stage packed K,V tiles: wave w stages fragments w*4..w*4+3 of each
            {
                const u16* ks = Kpb + (size_t)kt * 8192 + (w * 4) * 512 + lane * 8;
                const u16* vs = Vpb + (size_t)kt * 8192 + (w * 4) * 512 + lane * 8;
                #pragma unroll
                for (int i = 0; i < 4; i++) {
                    GLDS16(ks + i * 512, &Ks[(w * 4 + i) * 512]);
                    GLDS16(vs + i * 512, &Vs[(w * 4 + i) * 512]);
                }
            }
            __syncthreads();

            // QK^T (Q pre-scaled -> scores already in log2 domain)
            f4 sc[4];
            #pragma unroll
            for (int n = 0; n < 4; n++) sc[n] = (f4){0.f, 0.f, 0.f, 0.f};
            #pragma unroll
            for (int n = 0; n < 4; n++) {
                #pragma unroll
                for (int c = 0; c < 4; c++) {
                    short8 kf = *(const short8*)&Ks[(n * 4 + c) * 512 + lane * 8];
                    sc[n] = __builtin_amdgcn_mfma_f32_16x16x32_bf16(qf[c], kf, sc[n], 0, 0, 0);
                }
            }
            // causal mask only on the diagonal k-tile
            if (kt == nkt - 1) {
                int qrow0 = qt * 16 + quad * 4;
                #pragma unroll
                for (int n = 0; n < 4; n++) {
                    int colg = kt * 64 + n * 16 + l16;
                    #pragma unroll
                    for (int r = 0; r < 4; r++)
                        sc[n][r] = (colg <= qrow0 + r) ? sc[n][r] : -3e38f;
                }
            }
            // wave-group max (one scalar m per wave; exact — any per-row constant works)
            float gm = fmaxf(fmaxf(sc[0][0], sc[0][1]), fmaxf(sc[0][2], sc[0][3]));
            #pragma unroll
            for (int n = 1; n < 4; n++)
                gm = fmaxf(gm, fmaxf(fmaxf(sc[n][0], sc[n][1]), fmaxf(sc[n][2], sc[n][3])));
            #pragma unroll
            for (int off = 1; off < 64; off <<= 1) gm = fmaxf(gm, __shfl_xor(gm, off, 64));
            float mnew = fmaxf(m_i, gm);
            if (mnew > m_i) {              // wave-uniform branch
                float al = exp2f(m_i - mnew);
                m_i = mnew;
                #pragma unroll
                for (int r = 0; r < 4; r++) ls[r] *= al;
                #pragma unroll
                for (int nt = 0; nt < 8; nt++)
                    #pragma unroll
                    for (int r = 0; r < 4; r++) o[nt][r] *= al;
            }
            // P = exp2(s - m), truncate-pack to bf16, swizzled LDS write
            #pragma unroll
            for (int n = 0; n < 4; n++) {
                #pragma unroll
                for (int r = 0; r < 4; r++) {
                    float p = exp2f(sc[n][r] - m_i);
                    union { float f; unsigned int u; } cv; cv.f = p;
                    int row = quad * 4 + r;
                    int sw = (n * 2 + hi) ^ (row & 7);
                    P[row * 64 + sw * 8 + l7] = (u16)(cv.u >> 16);
                }
            }
            __asm__ volatile("s_waitcnt lgkmcnt(0)" ::: "memory");

            // PV: O += P @ V ; l += P @ ones (MFMA row-sum)
            #pragma unroll
            for (int kc = 0; kc < 2; kc++) {
                short8 af = *(const short8*)&P[l16 * 64 + (((kc * 4 + quad) ^ l7) << 3)];
                ls = __builtin_amdgcn_mfma_f32_16x16x32_bf16(af, ones, ls, 0, 0, 0);
                #pragma unroll
                for (int nt = 0; nt < 8; nt++) {
                    short8 vf = *(const short8*)&Vs[(nt * 2 + kc) * 512 + lane * 8];
                    o[nt] = __builtin_amdgcn_mfma_f32_16x16x32_bf16(af, vf, o[nt], 0, 0, 0);
                }
            }
            __syncthreads();
        }
        // epilogue for this q-tile
        float rl[4];
        #pragma unroll
        for (int r = 0; r < 4; r++) rl[r] = 1.0f / ls[r];
        #pragma unroll
        for (int nt = 0; nt < 8; nt++)
            #pragma unroll
            for (int r = 0; r < 4; r++) {
                size_t row = (size_t)b * S_ + qt * 16 + quad * 4 + r;
                Ob[row * 2048 + h * HD_ + nt * 16 + l16] = f2bf(o[nt][r] * rl[r]);
            }
    }
}

extern "C" void kernel_launch(void* const* d_in, const int* in_sizes, int n_in,
                              void* d_out, int out_size, void* d_ws, size_t ws_size,
                              hipStream_t stream) {
    const float* x     = (const float*)d_in[0];
    const float* freqs = (const float*)d_in[1];
    const float* wq    = (const float*)d_in[2];
    const float* wk    = (const float*)d_in[3];
    const float* wv    = (const float*)d_in[4];
    const float* wo    = (const float*)d_in[5];
    float* out = (float*)d_out;

    char* p = (char*)d_ws;
    u16* xb    = (u16*)p; p += (size_t)4096 * 2048 * 2;   // 16MB
    u16* wqkvb = (u16*)p; p += (size_t)3072 * 2048 * 2;   // 12MB
    u16* wob   = (u16*)p; p += (size_t)2048 * 2048 * 2;   // 8MB
    u16* QKVb  = (u16*)p; p += (size_t)4096 * 3072 * 2;   // 24MB
    u16* Kpb   = (u16*)p; p += (size_t)8 * 32 * 8192 * 2; // 4MB
    u16* Vpb   = (u16*)p; p += (size_t)8 * 32 * 8192 * 2; // 4MB
    u16* attnb = xb;  // reuse

    cast_all<<<18432, 256, 0, stream>>>(x, wq, wk, wv, wo, xb, wqkvb, wob);

    gemm_bt<true><<<dim3(24, 32), 256, 0, stream>>>(xb, wqkvb, QKVb, 4096, 3072, 2048);

    rope_q<<<dim3(4, 4096), 256, 0, stream>>>(QKVb, freqs);

    pack_k<<<1024, 256, 0, stream>>>(QKVb, freqs, Kpb);
    pack_v<<<256, 256, 0, stream>>>(QKVb, Vpb);

    attn_kernel<<<512, 256, 0, stream>>>(QKVb, Kpb, Vpb, attnb);

    gemm_bt<false><<<dim3(16, 32), 256, 0, stream>>>(attnb, wob, out, 4096, 2048, 2048);
}